// Round 8
// baseline (13218.869 us; speedup 1.0000x reference)
//
#include <hip/hip_runtime.h>
#include <math.h>

#define D 256
#define SEQ 1000
#define NB 32
#define PATCH 160
#define NL 6
#define M_TOTAL (NB * SEQ)   // 32000
#define G3 (3 * D)           // 768

__device__ __forceinline__ float gelu_exact(float v) {
    return 0.5f * v * (1.0f + erff(v * 0.70710678118654752440f));
}

// Raw workgroup barrier: orders LDS (lgkmcnt) but does NOT drain vmcnt, so
// in-flight global stores (publish, x-writeback) cross steps without
// stalling. Exchange correctness comes from the packed token|payload match,
// not barrier-ordered visibility. (Harness-verified in rounds 3, 6, 7.)
__device__ __forceinline__ void bar_lds() {
    asm volatile("s_waitcnt lgkmcnt(0)" ::: "memory");
    __builtin_amdgcn_s_barrier();
    asm volatile("" ::: "memory");
}

// ---------------------------------------------------------------------------
// Kernel 1: conv patchify GEMM + exact GELU + pos_emb add
// ---------------------------------------------------------------------------
__global__ __launch_bounds__(256) void conv_gelu_pos(
    const float* __restrict__ wav, const float* __restrict__ cw,
    const float* __restrict__ pos, float* __restrict__ x)
{
    __shared__ float As[64][33];
    __shared__ float Bs[32][65];
    const int m0 = blockIdx.x * 64;
    const int n0 = blockIdx.y * 64;
    const int tid = threadIdx.x;
    const int tx = tid & 15;      // 0..15 -> n
    const int ty = tid >> 4;      // 0..15 -> m
    float acc[4][4] = {};

    for (int kc = 0; kc < PATCH; kc += 32) {
        for (int p = 0; p < 8; ++p) {
            int mr = p * 8 + (tid >> 5);
            int kk = tid & 31;
            int m = m0 + mr;
            int b = m / SEQ, s = m % SEQ;
            As[mr][kk] = wav[(size_t)b * 160000 + (size_t)s * PATCH + kc + kk];
        }
        for (int p = 0; p < 8; ++p) {
            int kr = p * 4 + (tid >> 6);
            int nn = tid & 63;
            Bs[kr][nn] = cw[(size_t)(kc + kr) * D + n0 + nn];
        }
        __syncthreads();
        #pragma unroll
        for (int kk = 0; kk < 32; ++kk) {
            float a[4], bb[4];
            #pragma unroll
            for (int i = 0; i < 4; ++i) a[i] = As[ty * 4 + i][kk];
            #pragma unroll
            for (int j = 0; j < 4; ++j) bb[j] = Bs[kk][tx * 4 + j];
            #pragma unroll
            for (int i = 0; i < 4; ++i)
                #pragma unroll
                for (int j = 0; j < 4; ++j)
                    acc[i][j] = fmaf(a[i], bb[j], acc[i][j]);
        }
        __syncthreads();
    }
    #pragma unroll
    for (int i = 0; i < 4; ++i) {
        int m = m0 + ty * 4 + i;
        int s = m % SEQ;
        int n = n0 + tx * 4;
        float4 v;
        v.x = gelu_exact(acc[i][0]) + pos[(size_t)s * D + n + 0];
        v.y = gelu_exact(acc[i][1]) + pos[(size_t)s * D + n + 1];
        v.z = gelu_exact(acc[i][2]) + pos[(size_t)s * D + n + 2];
        v.w = gelu_exact(acc[i][3]) + pos[(size_t)s * D + n + 3];
        *(float4*)&x[(size_t)m * D + n] = v;
    }
}

// ---------------------------------------------------------------------------
// Kernel 2: per-row mean / rstd (LayerNorm stats). One wave per row.
// ---------------------------------------------------------------------------
__global__ __launch_bounds__(64) void row_stats(
    const float* __restrict__ x, float* __restrict__ st)
{
    const int m = blockIdx.x;
    const int t = threadIdx.x;
    const float* r = x + (size_t)m * D;
    float s = 0.f, q = 0.f;
    #pragma unroll
    for (int i = 0; i < 4; ++i) {
        float v = r[t + 64 * i];
        s += v;
        q += v * v;
    }
    #pragma unroll
    for (int o = 32; o > 0; o >>= 1) {
        s += __shfl_down(s, o);
        q += __shfl_down(q, o);
    }
    if (t == 0) {
        float mu = s * (1.f / 256.f);
        float var = q * (1.f / 256.f) - mu * mu;
        st[2 * m]     = mu;
        st[2 * m + 1] = rsqrtf(var + 1e-5f);
    }
}

// ---------------------------------------------------------------------------
// Kernel 3: fused LN + input-projection GEMM
// ---------------------------------------------------------------------------
__global__ __launch_bounds__(256) void ln_xp_gemm(
    const float* __restrict__ x, const float* __restrict__ st,
    const float* __restrict__ lnsc, const float* __restrict__ lnbi,
    const float* __restrict__ wih, const float* __restrict__ bih,
    float* __restrict__ xp)
{
    __shared__ float As[64][33];
    __shared__ float Bs[32][65];
    __shared__ float sc[D], bi[D];
    const int m0 = blockIdx.x * 64;
    const int n0 = blockIdx.y * 64;
    const int tid = threadIdx.x;
    const int tx = tid & 15;
    const int ty = tid >> 4;
    sc[tid] = lnsc[tid];
    bi[tid] = lnbi[tid];
    float acc[4][4] = {};

    for (int kc = 0; kc < D; kc += 32) {
        for (int p = 0; p < 8; ++p) {
            int mr = p * 8 + (tid >> 5);
            int kk = tid & 31;
            int m = m0 + mr;
            float mu = st[2 * m], rs = st[2 * m + 1];
            float v = x[(size_t)m * D + kc + kk];
            As[mr][kk] = (v - mu) * rs * sc[kc + kk] + bi[kc + kk];
        }
        for (int p = 0; p < 8; ++p) {
            int nr = p * 8 + (tid >> 5);
            int kk = tid & 31;
            Bs[kk][nr] = wih[(size_t)(n0 + nr) * D + kc + kk];
        }
        __syncthreads();
        #pragma unroll
        for (int kk = 0; kk < 32; ++kk) {
            float a[4], bb[4];
            #pragma unroll
            for (int i = 0; i < 4; ++i) a[i] = As[ty * 4 + i][kk];
            #pragma unroll
            for (int j = 0; j < 4; ++j) bb[j] = Bs[kk][tx * 4 + j];
            #pragma unroll
            for (int i = 0; i < 4; ++i)
                #pragma unroll
                for (int j = 0; j < 4; ++j)
                    acc[i][j] = fmaf(a[i], bb[j], acc[i][j]);
        }
        __syncthreads();
    }
    #pragma unroll
    for (int i = 0; i < 4; ++i) {
        int m = m0 + ty * 4 + i;
        int n = n0 + tx * 4;
        float4 v;
        v.x = acc[i][0] + bih[n + 0];
        v.y = acc[i][1] + bih[n + 1];
        v.z = acc[i][2] + bih[n + 2];
        v.w = acc[i][3] + bih[n + 3];
        *(float4*)&xp[(size_t)m * G3 + n] = v;
    }
}

// ---------------------------------------------------------------------------
// Kernel 4: transpose w_hh [768][256] -> whT [256][768]
// ---------------------------------------------------------------------------
__global__ __launch_bounds__(256) void transpose_whh(
    const float* __restrict__ whh, float* __restrict__ whT)
{
    __shared__ float t[32][33];
    const int g0 = blockIdx.x * 32;
    const int k0 = blockIdx.y * 32;
    const int lx = threadIdx.x & 31;
    const int ly = threadIdx.x >> 5;   // 0..7
    for (int i = 0; i < 32; i += 8)
        t[ly + i][lx] = whh[(size_t)(g0 + ly + i) * D + k0 + lx];
    __syncthreads();
    for (int i = 0; i < 32; i += 8)
        whT[(size_t)(k0 + ly + i) * G3 + g0 + lx] = t[lx][ly + i];
}

// ---------------------------------------------------------------------------
// Kernel 4b: zero BOTH exchange buffers (once per launch). Tokens are exact-
// matched per (layer,step), so zeroed slots can never alias a live token.
// slow: 49152 u64 ; fast: 49152 u64 -> 98304 total.
// ---------------------------------------------------------------------------
__global__ __launch_bounds__(256) void zero_exch(unsigned long long* __restrict__ e)
{
    e[blockIdx.x * 256 + threadIdx.x] = 0ull;
}

// ---------------------------------------------------------------------------
// Kernel 5: GRU recurrence, K-SPLIT pair, register-resident weights,
// RACED dual-slot exchange (opportunistic same-XCD fast slot + proven slow).
//
// Round-7 post-mortem: step = publish(~600) + agent-scope transit (~2600-
// 2900cy, MALL/HBM-coherent) + gates. Transit is the whole game. The pair
// (bid, bid^8) lands on the same XCD under the documented %8 round-robin
// (same mapping T1's measured swizzle win relies on); same-XCD blocks could
// exchange through their shared L2 at ~10x lower latency. Rounds 4/5 hung
// because the fast path's LIVENESS depended on that unverifiable premise.
// This version makes liveness UNCONDITIONAL:
//   - producer double-publishes each word: fast slot (workgroup-scope store;
//     CDNA L1 is write-through so it lands in the producer's XCD L2) and
//     slow slot (agent-scope store; the proven r7 path).
//   - consumer's poll loop RACES both: each iteration checks the fast slot
//     via workgroup-scope fetch_add(0) (atomic RMWs execute at the
//     consumer's XCD L2 -- same L2 iff same XCD), THEN the slow slot via
//     agent-scope load. The loop always exits via the slow slot even if the
//     fast slot never becomes visible -> hang-free by construction.
//   - per-block kill switch: if no poller hit the fast slot during steps
//     0-1 (LDS vote), fast polling is skipped thereafter (cost ~= r7).
// Protocol per slot identical to proven r7: packed u64 token|payload,
// parity double-buffer, exact-token match, fixed combine order ->
// bitwise-identical results to r7 regardless of which slot wins.
// ---------------------------------------------------------------------------
__global__ __launch_bounds__(512, 2) void gru_scan_ksplit(
    const float* __restrict__ xp, const float* __restrict__ whT,
    const float* __restrict__ bhh, float* __restrict__ x,
    unsigned long long* exch_slow, unsigned long long* exch_fast, int layer)
{
    __shared__ float h_own[128];          // this block's h half
    __shared__ float prA[3][3][128];      // peer-dout partials [kq-1][gate][dd]
    __shared__ float prB[3][3][128];      // own-dout partials
    __shared__ float peerP[3][128];       // received peer partials [gate][dd]
    __shared__ unsigned int fastHits;
    __shared__ int fastDead;
    const int tid  = threadIdx.x;
    const int kq   = tid >> 7;            // 0..3 (wave-uniform: 2 waves/kq)
    const int dd   = tid & 127;
    const int bid  = blockIdx.x;
    // pair (bid, bid^8): same XCD under %8 round-robin dispatch (fast-slot
    // bet only; correctness never depends on it)
    const int half  = (bid >> 3) & 1;               // K half owned
    const int batch = (bid & 7) * 4 + (bid >> 4);   // 0..31, same for pair
    const int odout = half * 128 + dd;              // own output dim
    const int pdout = (1 - half) * 128 + dd;        // peer-owned output dim
    const int kbase = half * 128 + kq * 32;         // K rows this thread covers

    // --- resident weights: 6 gate-columns x 32 K = 192 floats --------------
    float wpr[32], wpz[32], wpn[32], wor[32], woz[32], won[32];
    {
        const float* wb = whT + (size_t)kbase * G3;
        #pragma unroll
        for (int j = 0; j < 32; ++j) {
            const float* wr_ = wb + (size_t)j * G3;
            wpr[j] = wr_[pdout]; wpz[j] = wr_[D + pdout]; wpn[j] = wr_[2 * D + pdout];
            wor[j] = wr_[odout]; woz[j] = wr_[D + odout]; won[j] = wr_[2 * D + odout];
        }
    }
    const float bh_r = bhh[odout];
    const float bh_z = bhh[D + odout];
    const float bh_n = bhh[2 * D + odout];

    const size_t mySlot   = (size_t)(batch * 2 + half)       * 2 * 384;
    const size_t peerSlot = (size_t)(batch * 2 + (1 - half)) * 2 * 384;
    unsigned long long*       pubS = exch_slow + mySlot;
    unsigned long long*       pubF = exch_fast + mySlot;
    const unsigned long long* subS = exch_slow + peerSlot;
    unsigned long long*       subF = exch_fast + peerSlot;

    const float* xpb = xp + (size_t)batch * SEQ * G3;
    float* xb = x + (size_t)batch * SEQ * D;

    if (tid < 128) h_own[tid] = 0.f;
    if (tid == 0) { fastHits = 0u; fastDead = 0; }
    __syncthreads();

    const unsigned int tok0 = (unsigned int)layer * SEQ + 1u;
    for (int t = 0; t < SEQ; ++t) {
        const unsigned int token = tok0 + (unsigned int)t;
        const int par = t & 1;

        // issue xp + residual loads early; latency hides under FMA phases
        float xr = 0.f, xz = 0.f, xn_ = 0.f, xold = 0.f;
        if (kq == 0) {
            const float* xpt = xpb + (size_t)t * G3;
            xr   = xpt[odout];
            xz   = xpt[D + odout];
            xn_  = xpt[2 * D + odout];
            xold = xb[(size_t)t * D + odout];
        }

        // --- phase A: partials for PEER douts over own K quarter -----------
        float ar = 0.f, az = 0.f, an = 0.f;
        {
            const float* hb = &h_own[kq * 32];
            #pragma unroll
            for (int q = 0; q < 8; ++q) {
                float4 hv = *(const float4*)(hb + q * 4);   // uniform bcast
                ar = fmaf(hv.x, wpr[4*q+0], ar); az = fmaf(hv.x, wpz[4*q+0], az); an = fmaf(hv.x, wpn[4*q+0], an);
                ar = fmaf(hv.y, wpr[4*q+1], ar); az = fmaf(hv.y, wpz[4*q+1], az); an = fmaf(hv.y, wpn[4*q+1], an);
                ar = fmaf(hv.z, wpr[4*q+2], ar); az = fmaf(hv.z, wpz[4*q+2], az); an = fmaf(hv.z, wpn[4*q+2], an);
                ar = fmaf(hv.w, wpr[4*q+3], ar); az = fmaf(hv.w, wpz[4*q+3], az); an = fmaf(hv.w, wpn[4*q+3], an);
            }
        }
        if (kq) { prA[kq-1][0][dd] = ar; prA[kq-1][1][dd] = az; prA[kq-1][2][dd] = an; }
        bar_lds();

        // --- kq0: combine + DOUBLE-PUBLISH (fast L2 slot, then slow) -------
        if (kq == 0) {
            ar += prA[0][0][dd] + prA[1][0][dd] + prA[2][0][dd];
            az += prA[0][1][dd] + prA[1][1][dd] + prA[2][1][dd];
            an += prA[0][2][dd] + prA[1][2][dd] + prA[2][2][dd];
            unsigned long long hi = ((unsigned long long)token << 32);
            unsigned long long wr_ = hi | __float_as_uint(ar);
            unsigned long long wz_ = hi | __float_as_uint(az);
            unsigned long long wn_ = hi | __float_as_uint(an);
            unsigned long long* pf = pubF + (size_t)par * 384;
            __hip_atomic_store(pf +       dd, wr_, __ATOMIC_RELAXED, __HIP_MEMORY_SCOPE_WORKGROUP);
            __hip_atomic_store(pf + 128 + dd, wz_, __ATOMIC_RELAXED, __HIP_MEMORY_SCOPE_WORKGROUP);
            __hip_atomic_store(pf + 256 + dd, wn_, __ATOMIC_RELAXED, __HIP_MEMORY_SCOPE_WORKGROUP);
            unsigned long long* ps = pubS + (size_t)par * 384;
            __hip_atomic_store(ps +       dd, wr_, __ATOMIC_RELAXED, __HIP_MEMORY_SCOPE_AGENT);
            __hip_atomic_store(ps + 128 + dd, wz_, __ATOMIC_RELAXED, __HIP_MEMORY_SCOPE_AGENT);
            __hip_atomic_store(ps + 256 + dd, wn_, __ATOMIC_RELAXED, __HIP_MEMORY_SCOPE_AGENT);
        }

        // --- phase B: partials for OWN douts (overlaps the transit) --------
        float br = 0.f, bz = 0.f, bn = 0.f;
        {
            const float* hb = &h_own[kq * 32];
            #pragma unroll
            for (int q = 0; q < 8; ++q) {
                float4 hv = *(const float4*)(hb + q * 4);
                br = fmaf(hv.x, wor[4*q+0], br); bz = fmaf(hv.x, woz[4*q+0], bz); bn = fmaf(hv.x, won[4*q+0], bn);
                br = fmaf(hv.y, wor[4*q+1], br); bz = fmaf(hv.y, woz[4*q+1], bz); bn = fmaf(hv.y, won[4*q+1], bn);
                br = fmaf(hv.z, wor[4*q+2], br); bz = fmaf(hv.z, woz[4*q+2], bz); bn = fmaf(hv.z, won[4*q+2], bn);
                br = fmaf(hv.w, wor[4*q+3], br); bz = fmaf(hv.w, woz[4*q+3], bz); bn = fmaf(hv.w, won[4*q+3], bn);
            }
        }
        if (kq) { prB[kq-1][0][dd] = br; prB[kq-1][1][dd] = bz; prB[kq-1][2][dd] = bn; }
        bar_lds();

        // --- poll peer partials (raced fast/slow); kq0 combines own --------
        if (kq == 0) {
            br += prB[0][0][dd] + prB[1][0][dd] + prB[2][0][dd];
            bz += prB[0][1][dd] + prB[1][1][dd] + prB[2][1][dd];
            bn += prB[0][2][dd] + prB[1][2][dd] + prB[2][2][dd];
        } else {
            const size_t idx = (size_t)par * 384 + (size_t)(kq - 1) * 128 + dd;
            unsigned long long w;
            if (!fastDead) {
                bool viaFast = false;
                for (;;) {
                    unsigned long long wf = __hip_atomic_fetch_add(
                        &subF[idx], 0ull, __ATOMIC_RELAXED,
                        __HIP_MEMORY_SCOPE_WORKGROUP);
                    if ((unsigned int)(wf >> 32) == token) { w = wf; viaFast = true; break; }
                    unsigned long long ws2 = __hip_atomic_load(
                        &subS[idx], __ATOMIC_RELAXED, __HIP_MEMORY_SCOPE_AGENT);
                    if ((unsigned int)(ws2 >> 32) == token) { w = ws2; break; }
                }
                if (t < 2 && viaFast) atomicAdd(&fastHits, 1u);
            } else {
                do {
                    w = __hip_atomic_load(&subS[idx], __ATOMIC_RELAXED,
                                          __HIP_MEMORY_SCOPE_AGENT);
                } while ((unsigned int)(w >> 32) != token);
            }
            peerP[kq - 1][dd] = __uint_as_float((unsigned int)w);
        }
        bar_lds();

        // --- gates + local h update ----------------------------------------
        if (kq == 0) {
            float gr = xr + br + peerP[0][dd] + bh_r;
            float gz = xz + bz + peerP[1][dd] + bh_z;
            float gn =      bn + peerP[2][dd] + bh_n;
            float r = 1.f / (1.f + expf(-gr));
            float z = 1.f / (1.f + expf(-gz));
            float n = tanhf(xn_ + r * gn);
            float hnew = (1.f - z) * n + z * h_own[dd];
            h_own[dd] = hnew;
            xb[(size_t)t * D + odout] = xold + hnew;
        }
        if (t == 1 && tid == 0 && fastHits == 0u) fastDead = 1;  // vote result
        bar_lds();
    }
}

// ---------------------------------------------------------------------------
// Kernel 6: final LN + mean-pool over sequence
// ---------------------------------------------------------------------------
__global__ __launch_bounds__(256) void pool_ln(
    const float* __restrict__ x, const float* __restrict__ st,
    const float* __restrict__ fsc, const float* __restrict__ fbi,
    float* __restrict__ emb)
{
    const int b = blockIdx.x;
    const int d = threadIdx.x;
    float acc = 0.f;
    for (int s = 0; s < SEQ; ++s) {
        int m = b * SEQ + s;
        acc += (x[(size_t)m * D + d] - st[2 * m]) * st[2 * m + 1];
    }
    emb[b * D + d] = (acc * (1.f / (float)SEQ)) * fsc[d] + fbi[d];
}

// ---------------------------------------------------------------------------
// Kernel 7: classification head (tiny). Single block.
// ---------------------------------------------------------------------------
__global__ __launch_bounds__(256) void head_mlp(
    const float* __restrict__ emb, const float* __restrict__ w1,
    const float* __restrict__ b1, const float* __restrict__ w2,
    const float* __restrict__ b2, float* __restrict__ out)
{
    __shared__ float es[NB][D + 1];
    __shared__ float h1[NB][128 + 1];
    const int t = threadIdx.x;
    for (int i = t; i < NB * D; i += 256) es[i / D][i % D] = emb[i];
    __syncthreads();
    for (int i = t; i < NB * 128; i += 256) {
        int bb = i / 128, j = i % 128;
        float a = b1[j];
        for (int k = 0; k < D; ++k) a = fmaf(es[bb][k], w1[(size_t)k * 128 + j], a);
        h1[bb][j] = gelu_exact(a);
    }
    __syncthreads();
    for (int i = t; i < NB * 8; i += 256) {
        int bb = i / 8, c = i % 8;
        float a = b2[c];
        for (int k = 0; k < 128; ++k) a = fmaf(h1[bb][k], w2[(size_t)k * 8 + c], a);
        out[i] = a;
    }
}

// ---------------------------------------------------------------------------
extern "C" void kernel_launch(void* const* d_in, const int* in_sizes, int n_in,
                              void* d_out, int out_size, void* d_ws, size_t ws_size,
                              hipStream_t stream)
{
    const float* wav  = (const float*)d_in[0];
    const float* cw   = (const float*)d_in[1];
    const float* pos  = (const float*)d_in[2];
    const float* lnsc = (const float*)d_in[3];
    const float* lnbi = (const float*)d_in[4];
    const float* wih  = (const float*)d_in[5];
    const float* whh  = (const float*)d_in[6];
    const float* bih  = (const float*)d_in[7];
    const float* bhh  = (const float*)d_in[8];
    const float* fsc  = (const float*)d_in[9];
    const float* fbi  = (const float*)d_in[10];
    const float* hw1  = (const float*)d_in[11];
    const float* hb1  = (const float*)d_in[12];
    const float* hw2  = (const float*)d_in[13];
    const float* hb2  = (const float*)d_in[14];

    float* ws    = (float*)d_ws;
    float* x     = ws;                        // 8,192,000 f
    float* xp    = x + (size_t)M_TOTAL * D;   // 24,576,000 f
    float* st    = xp + (size_t)M_TOTAL * G3; // 64,000 f
    float* whT   = st + 2 * M_TOTAL;          // 196,608 f
    float* emb   = whT + D * G3;              // 8,192 f
    unsigned long long* exch_slow = (unsigned long long*)(emb + NB * D); // 49152 u64
    unsigned long long* exch_fast = exch_slow + 49152;                   // 49152 u64

    zero_exch<<<384, 256, 0, stream>>>(exch_slow);  // zeroes slow+fast (contiguous)
    conv_gelu_pos<<<dim3(M_TOTAL / 64, D / 64), 256, 0, stream>>>(wav, cw, pos, x);

    for (int l = 0; l < NL; ++l) {
        row_stats<<<M_TOTAL, 64, 0, stream>>>(x, st);
        ln_xp_gemm<<<dim3(M_TOTAL / 64, G3 / 64), 256, 0, stream>>>(
            x, st, lnsc + (size_t)l * D, lnbi + (size_t)l * D,
            wih + (size_t)l * G3 * D, bih + (size_t)l * G3, xp);
        transpose_whh<<<dim3(G3 / 32, D / 32), 256, 0, stream>>>(
            whh + (size_t)l * G3 * D, whT);
        gru_scan_ksplit<<<NB * 2, 512, 0, stream>>>(
            xp, whT, bhh + (size_t)l * G3, x, exch_slow, exch_fast, l);
    }

    row_stats<<<M_TOTAL, 64, 0, stream>>>(x, st);
    pool_ln<<<NB, D, 0, stream>>>(x, st, fsc, fbi, emb);
    head_mlp<<<1, 256, 0, stream>>>(emb, hw1, hb1, hw2, hb2, (float*)d_out);
}

// Round 9
// 11424.820 us; speedup vs baseline: 1.1570x; 1.1570x over previous
//
#include <hip/hip_runtime.h>
#include <math.h>

#define D 256
#define SEQ 1000
#define NB 32
#define PATCH 160
#define NL 6
#define M_TOTAL (NB * SEQ)   // 32000
#define G3 (3 * D)           // 768

__device__ __forceinline__ float gelu_exact(float v) {
    return 0.5f * v * (1.0f + erff(v * 0.70710678118654752440f));
}

// Raw workgroup barrier: orders LDS (lgkmcnt) but does NOT drain vmcnt, so
// in-flight global stores (publish, x-writeback) cross steps without
// stalling. Exchange correctness comes from the packed token|payload match,
// not barrier-ordered visibility. (Harness-verified in rounds 3, 6, 7.)
__device__ __forceinline__ void bar_lds() {
    asm volatile("s_waitcnt lgkmcnt(0)" ::: "memory");
    __builtin_amdgcn_s_barrier();
    asm volatile("" ::: "memory");
}

// ---------------------------------------------------------------------------
// Kernel 1: conv patchify GEMM + exact GELU + pos_emb add
// ---------------------------------------------------------------------------
__global__ __launch_bounds__(256) void conv_gelu_pos(
    const float* __restrict__ wav, const float* __restrict__ cw,
    const float* __restrict__ pos, float* __restrict__ x)
{
    __shared__ float As[64][33];
    __shared__ float Bs[32][65];
    const int m0 = blockIdx.x * 64;
    const int n0 = blockIdx.y * 64;
    const int tid = threadIdx.x;
    const int tx = tid & 15;      // 0..15 -> n
    const int ty = tid >> 4;      // 0..15 -> m
    float acc[4][4] = {};

    for (int kc = 0; kc < PATCH; kc += 32) {
        for (int p = 0; p < 8; ++p) {
            int mr = p * 8 + (tid >> 5);
            int kk = tid & 31;
            int m = m0 + mr;
            int b = m / SEQ, s = m % SEQ;
            As[mr][kk] = wav[(size_t)b * 160000 + (size_t)s * PATCH + kc + kk];
        }
        for (int p = 0; p < 8; ++p) {
            int kr = p * 4 + (tid >> 6);
            int nn = tid & 63;
            Bs[kr][nn] = cw[(size_t)(kc + kr) * D + n0 + nn];
        }
        __syncthreads();
        #pragma unroll
        for (int kk = 0; kk < 32; ++kk) {
            float a[4], bb[4];
            #pragma unroll
            for (int i = 0; i < 4; ++i) a[i] = As[ty * 4 + i][kk];
            #pragma unroll
            for (int j = 0; j < 4; ++j) bb[j] = Bs[kk][tx * 4 + j];
            #pragma unroll
            for (int i = 0; i < 4; ++i)
                #pragma unroll
                for (int j = 0; j < 4; ++j)
                    acc[i][j] = fmaf(a[i], bb[j], acc[i][j]);
        }
        __syncthreads();
    }
    #pragma unroll
    for (int i = 0; i < 4; ++i) {
        int m = m0 + ty * 4 + i;
        int s = m % SEQ;
        int n = n0 + tx * 4;
        float4 v;
        v.x = gelu_exact(acc[i][0]) + pos[(size_t)s * D + n + 0];
        v.y = gelu_exact(acc[i][1]) + pos[(size_t)s * D + n + 1];
        v.z = gelu_exact(acc[i][2]) + pos[(size_t)s * D + n + 2];
        v.w = gelu_exact(acc[i][3]) + pos[(size_t)s * D + n + 3];
        *(float4*)&x[(size_t)m * D + n] = v;
    }
}

// ---------------------------------------------------------------------------
// Kernel 2: per-row mean / rstd (LayerNorm stats). One wave per row.
// ---------------------------------------------------------------------------
__global__ __launch_bounds__(64) void row_stats(
    const float* __restrict__ x, float* __restrict__ st)
{
    const int m = blockIdx.x;
    const int t = threadIdx.x;
    const float* r = x + (size_t)m * D;
    float s = 0.f, q = 0.f;
    #pragma unroll
    for (int i = 0; i < 4; ++i) {
        float v = r[t + 64 * i];
        s += v;
        q += v * v;
    }
    #pragma unroll
    for (int o = 32; o > 0; o >>= 1) {
        s += __shfl_down(s, o);
        q += __shfl_down(q, o);
    }
    if (t == 0) {
        float mu = s * (1.f / 256.f);
        float var = q * (1.f / 256.f) - mu * mu;
        st[2 * m]     = mu;
        st[2 * m + 1] = rsqrtf(var + 1e-5f);
    }
}

// ---------------------------------------------------------------------------
// Kernel 3: fused LN + input-projection GEMM
// ---------------------------------------------------------------------------
__global__ __launch_bounds__(256) void ln_xp_gemm(
    const float* __restrict__ x, const float* __restrict__ st,
    const float* __restrict__ lnsc, const float* __restrict__ lnbi,
    const float* __restrict__ wih, const float* __restrict__ bih,
    float* __restrict__ xp)
{
    __shared__ float As[64][33];
    __shared__ float Bs[32][65];
    __shared__ float sc[D], bi[D];
    const int m0 = blockIdx.x * 64;
    const int n0 = blockIdx.y * 64;
    const int tid = threadIdx.x;
    const int tx = tid & 15;
    const int ty = tid >> 4;
    sc[tid] = lnsc[tid];
    bi[tid] = lnbi[tid];
    float acc[4][4] = {};

    for (int kc = 0; kc < D; kc += 32) {
        for (int p = 0; p < 8; ++p) {
            int mr = p * 8 + (tid >> 5);
            int kk = tid & 31;
            int m = m0 + mr;
            float mu = st[2 * m], rs = st[2 * m + 1];
            float v = x[(size_t)m * D + kc + kk];
            As[mr][kk] = (v - mu) * rs * sc[kc + kk] + bi[kc + kk];
        }
        for (int p = 0; p < 8; ++p) {
            int nr = p * 8 + (tid >> 5);
            int kk = tid & 31;
            Bs[kk][nr] = wih[(size_t)(n0 + nr) * D + kc + kk];
        }
        __syncthreads();
        #pragma unroll
        for (int kk = 0; kk < 32; ++kk) {
            float a[4], bb[4];
            #pragma unroll
            for (int i = 0; i < 4; ++i) a[i] = As[ty * 4 + i][kk];
            #pragma unroll
            for (int j = 0; j < 4; ++j) bb[j] = Bs[kk][tx * 4 + j];
            #pragma unroll
            for (int i = 0; i < 4; ++i)
                #pragma unroll
                for (int j = 0; j < 4; ++j)
                    acc[i][j] = fmaf(a[i], bb[j], acc[i][j]);
        }
        __syncthreads();
    }
    #pragma unroll
    for (int i = 0; i < 4; ++i) {
        int m = m0 + ty * 4 + i;
        int n = n0 + tx * 4;
        float4 v;
        v.x = acc[i][0] + bih[n + 0];
        v.y = acc[i][1] + bih[n + 1];
        v.z = acc[i][2] + bih[n + 2];
        v.w = acc[i][3] + bih[n + 3];
        *(float4*)&xp[(size_t)m * G3 + n] = v;
    }
}

// ---------------------------------------------------------------------------
// Kernel 4: transpose w_hh [768][256] -> whT [256][768]
// ---------------------------------------------------------------------------
__global__ __launch_bounds__(256) void transpose_whh(
    const float* __restrict__ whh, float* __restrict__ whT)
{
    __shared__ float t[32][33];
    const int g0 = blockIdx.x * 32;
    const int k0 = blockIdx.y * 32;
    const int lx = threadIdx.x & 31;
    const int ly = threadIdx.x >> 5;   // 0..7
    for (int i = 0; i < 32; i += 8)
        t[ly + i][lx] = whh[(size_t)(g0 + ly + i) * D + k0 + lx];
    __syncthreads();
    for (int i = 0; i < 32; i += 8)
        whT[(size_t)(k0 + ly + i) * G3 + g0 + lx] = t[lx][ly + i];
}

// ---------------------------------------------------------------------------
// Kernel 4b: zero the exchange buffer (once per launch). Tokens are exact-
// matched per (layer,step), so zeroed slots can never alias a live token.
// 32 batches x 2 halves x 2 parities x 384 u64 = 49152 u64.
// ---------------------------------------------------------------------------
__global__ __launch_bounds__(256) void zero_exch(unsigned long long* __restrict__ e)
{
    e[blockIdx.x * 256 + threadIdx.x] = 0ull;
}

// ---------------------------------------------------------------------------
// Kernel 5: GRU recurrence, K-SPLIT pair, register-resident weights.
//
// Round-8 post-mortem: the raced same-XCD fast slot regressed (+18% GRU) --
// the same-XCD premise is empirically dead on this harness (hang, hang,
// regression). This is r7 (best: 11.22ms) + two protocol-identical
// micro-optimizations on the PROVEN agent-scope exchange:
//   1. DISTRIBUTED COMBINE+PUBLISH: all 4 kq groups store phase-A partials
//      to LDS; kq1/kq2/kq3 each combine ONE gate (same left-to-right chunk
//      order -> bitwise-identical to r7) and publish its 128 words in
//      parallel. Publish lands ~120cy earlier, 1 store/thread (vs 3
//      serialized on kq0).
//   2. STAGGERED-RING POLL: 4 agent-scope loads kept in flight, paced
//      ~64-100cy apart via s_sleep(1), checked oldest-first. Discovery
//      granularity drops from a full MALL round trip (~600-900cy, the
//      serialized-poll period) to ~100cy. Liveness identical to r7: same
//      slot, same exact-token exit, ring always reissues.
// Protocol: packed u64 token|payload, parity double-buffer, exact-token
// match, fixed combine order -> race-free by the proven induction,
// bitwise-identical output to r7.
// ---------------------------------------------------------------------------
__global__ __launch_bounds__(512, 2) void gru_scan_ksplit(
    const float* __restrict__ xp, const float* __restrict__ whT,
    const float* __restrict__ bhh, float* __restrict__ x,
    unsigned long long* exch, int layer)
{
    __shared__ float h_own[128];          // this block's h half
    __shared__ float prA[4][3][128];      // peer-dout partials [chunk][gate][dd]
    __shared__ float prB[3][3][128];      // own-dout partials [kq-1][gate][dd]
    __shared__ float peerP[3][128];       // received peer partials [gate][dd]
    const int tid  = threadIdx.x;
    const int kq   = tid >> 7;            // 0..3 (wave-uniform: 2 waves/kq)
    const int dd   = tid & 127;
    const int batch = blockIdx.x >> 1;
    const int half  = blockIdx.x & 1;     // K half owned: [128h, 128h+128)
    const int odout = half * 128 + dd;          // own output dim
    const int pdout = (1 - half) * 128 + dd;    // peer-owned output dim
    const int kbase = half * 128 + kq * 32;     // K rows this thread covers

    // --- resident weights: 6 gate-columns x 32 K = 192 floats --------------
    float wpr[32], wpz[32], wpn[32], wor[32], woz[32], won[32];
    {
        const float* wb = whT + (size_t)kbase * G3;
        #pragma unroll
        for (int j = 0; j < 32; ++j) {
            const float* wr_ = wb + (size_t)j * G3;
            wpr[j] = wr_[pdout]; wpz[j] = wr_[D + pdout]; wpn[j] = wr_[2 * D + pdout];
            wor[j] = wr_[odout]; woz[j] = wr_[D + odout]; won[j] = wr_[2 * D + odout];
        }
    }
    const float bh_r = bhh[odout];
    const float bh_z = bhh[D + odout];
    const float bh_n = bhh[2 * D + odout];

    unsigned long long*       pub = exch + (size_t)(batch * 2 + half)       * 2 * 384;
    const unsigned long long* sub = exch + (size_t)(batch * 2 + (1 - half)) * 2 * 384;

    const float* xpb = xp + (size_t)batch * SEQ * G3;
    float* xb = x + (size_t)batch * SEQ * D;

    if (tid < 128) h_own[tid] = 0.f;
    __syncthreads();

    const unsigned int tok0 = (unsigned int)layer * SEQ + 1u;
    for (int t = 0; t < SEQ; ++t) {
        const unsigned int token = tok0 + (unsigned int)t;
        const int par = t & 1;

        // issue xp + residual loads early; latency hides under FMA phases
        float xr = 0.f, xz = 0.f, xn_ = 0.f, xold = 0.f;
        if (kq == 0) {
            const float* xpt = xpb + (size_t)t * G3;
            xr   = xpt[odout];
            xz   = xpt[D + odout];
            xn_  = xpt[2 * D + odout];
            xold = xb[(size_t)t * D + odout];
        }

        // --- phase A: partials for PEER douts over own K quarter -----------
        float ar = 0.f, az = 0.f, an = 0.f;
        {
            const float* hb = &h_own[kq * 32];
            #pragma unroll
            for (int q = 0; q < 8; ++q) {
                float4 hv = *(const float4*)(hb + q * 4);   // uniform bcast
                ar = fmaf(hv.x, wpr[4*q+0], ar); az = fmaf(hv.x, wpz[4*q+0], az); an = fmaf(hv.x, wpn[4*q+0], an);
                ar = fmaf(hv.y, wpr[4*q+1], ar); az = fmaf(hv.y, wpz[4*q+1], az); an = fmaf(hv.y, wpn[4*q+1], an);
                ar = fmaf(hv.z, wpr[4*q+2], ar); az = fmaf(hv.z, wpz[4*q+2], az); an = fmaf(hv.z, wpn[4*q+2], an);
                ar = fmaf(hv.w, wpr[4*q+3], ar); az = fmaf(hv.w, wpz[4*q+3], az); an = fmaf(hv.w, wpn[4*q+3], an);
            }
        }
        prA[kq][0][dd] = ar; prA[kq][1][dd] = az; prA[kq][2][dd] = an;
        bar_lds();

        // --- distributed combine + publish: kq g+1 handles gate g ----------
        // chunk order 0,1,2,3 left-to-right == r7's (kq0 + kq1 + kq2 + kq3)
        if (kq) {
            const int g = kq - 1;
            float p = ((prA[0][g][dd] + prA[1][g][dd]) + prA[2][g][dd]) + prA[3][g][dd];
            __hip_atomic_store(pub + (size_t)par * 384 + g * 128 + dd,
                               ((unsigned long long)token << 32) |
                               (unsigned long long)__float_as_uint(p),
                               __ATOMIC_RELAXED, __HIP_MEMORY_SCOPE_AGENT);
        }

        // --- phase B: partials for OWN douts (overlaps the transit) --------
        float br = 0.f, bz = 0.f, bn = 0.f;
        {
            const float* hb = &h_own[kq * 32];
            #pragma unroll
            for (int q = 0; q < 8; ++q) {
                float4 hv = *(const float4*)(hb + q * 4);
                br = fmaf(hv.x, wor[4*q+0], br); bz = fmaf(hv.x, woz[4*q+0], bz); bn = fmaf(hv.x, won[4*q+0], bn);
                br = fmaf(hv.y, wor[4*q+1], br); bz = fmaf(hv.y, woz[4*q+1], bz); bn = fmaf(hv.y, won[4*q+1], bn);
                br = fmaf(hv.z, wor[4*q+2], br); bz = fmaf(hv.z, woz[4*q+2], bz); bn = fmaf(hv.z, won[4*q+2], bn);
                br = fmaf(hv.w, wor[4*q+3], br); bz = fmaf(hv.w, woz[4*q+3], bz); bn = fmaf(hv.w, won[4*q+3], bn);
            }
        }
        if (kq) { prB[kq-1][0][dd] = br; prB[kq-1][1][dd] = bz; prB[kq-1][2][dd] = bn; }
        bar_lds();

        // --- poll peer partials (staggered ring); kq0 combines own ---------
        if (kq == 0) {
            br += prB[0][0][dd] + prB[1][0][dd] + prB[2][0][dd];
            bz += prB[0][1][dd] + prB[1][1][dd] + prB[2][1][dd];
            bn += prB[0][2][dd] + prB[1][2][dd] + prB[2][2][dd];
        } else {
            const unsigned long long* qw =
                sub + (size_t)par * 384 + (size_t)(kq - 1) * 128 + dd;
            unsigned long long w;
            // 4-deep staggered ring: samples the slot every ~64-100cy
            // instead of every MALL round trip. Exit ONLY on exact token
            // match (liveness identical to the proven serialized poll).
            unsigned long long s0, s1, s2, s3;
            s0 = __hip_atomic_load(qw, __ATOMIC_RELAXED, __HIP_MEMORY_SCOPE_AGENT);
            __builtin_amdgcn_s_sleep(1);
            s1 = __hip_atomic_load(qw, __ATOMIC_RELAXED, __HIP_MEMORY_SCOPE_AGENT);
            __builtin_amdgcn_s_sleep(1);
            s2 = __hip_atomic_load(qw, __ATOMIC_RELAXED, __HIP_MEMORY_SCOPE_AGENT);
            __builtin_amdgcn_s_sleep(1);
            s3 = __hip_atomic_load(qw, __ATOMIC_RELAXED, __HIP_MEMORY_SCOPE_AGENT);
            for (;;) {
                if ((unsigned int)(s0 >> 32) == token) { w = s0; break; }
                __builtin_amdgcn_s_sleep(1);
                s0 = __hip_atomic_load(qw, __ATOMIC_RELAXED, __HIP_MEMORY_SCOPE_AGENT);
                if ((unsigned int)(s1 >> 32) == token) { w = s1; break; }
                __builtin_amdgcn_s_sleep(1);
                s1 = __hip_atomic_load(qw, __ATOMIC_RELAXED, __HIP_MEMORY_SCOPE_AGENT);
                if ((unsigned int)(s2 >> 32) == token) { w = s2; break; }
                __builtin_amdgcn_s_sleep(1);
                s2 = __hip_atomic_load(qw, __ATOMIC_RELAXED, __HIP_MEMORY_SCOPE_AGENT);
                if ((unsigned int)(s3 >> 32) == token) { w = s3; break; }
                __builtin_amdgcn_s_sleep(1);
                s3 = __hip_atomic_load(qw, __ATOMIC_RELAXED, __HIP_MEMORY_SCOPE_AGENT);
            }
            peerP[kq - 1][dd] = __uint_as_float((unsigned int)w);
        }
        bar_lds();

        // --- gates + local h update ----------------------------------------
        if (kq == 0) {
            float gr = xr + br + peerP[0][dd] + bh_r;
            float gz = xz + bz + peerP[1][dd] + bh_z;
            float gn =      bn + peerP[2][dd] + bh_n;
            float r = 1.f / (1.f + expf(-gr));
            float z = 1.f / (1.f + expf(-gz));
            float n = tanhf(xn_ + r * gn);
            float hnew = (1.f - z) * n + z * h_own[dd];
            h_own[dd] = hnew;
            xb[(size_t)t * D + odout] = xold + hnew;
        }
        bar_lds();
    }
}

// ---------------------------------------------------------------------------
// Kernel 6: final LN + mean-pool over sequence
// ---------------------------------------------------------------------------
__global__ __launch_bounds__(256) void pool_ln(
    const float* __restrict__ x, const float* __restrict__ st,
    const float* __restrict__ fsc, const float* __restrict__ fbi,
    float* __restrict__ emb)
{
    const int b = blockIdx.x;
    const int d = threadIdx.x;
    float acc = 0.f;
    for (int s = 0; s < SEQ; ++s) {
        int m = b * SEQ + s;
        acc += (x[(size_t)m * D + d] - st[2 * m]) * st[2 * m + 1];
    }
    emb[b * D + d] = (acc * (1.f / (float)SEQ)) * fsc[d] + fbi[d];
}

// ---------------------------------------------------------------------------
// Kernel 7: classification head (tiny). Single block.
// ---------------------------------------------------------------------------
__global__ __launch_bounds__(256) void head_mlp(
    const float* __restrict__ emb, const float* __restrict__ w1,
    const float* __restrict__ b1, const float* __restrict__ w2,
    const float* __restrict__ b2, float* __restrict__ out)
{
    __shared__ float es[NB][D + 1];
    __shared__ float h1[NB][128 + 1];
    const int t = threadIdx.x;
    for (int i = t; i < NB * D; i += 256) es[i / D][i % D] = emb[i];
    __syncthreads();
    for (int i = t; i < NB * 128; i += 256) {
        int bb = i / 128, j = i % 128;
        float a = b1[j];
        for (int k = 0; k < D; ++k) a = fmaf(es[bb][k], w1[(size_t)k * 128 + j], a);
        h1[bb][j] = gelu_exact(a);
    }
    __syncthreads();
    for (int i = t; i < NB * 8; i += 256) {
        int bb = i / 8, c = i % 8;
        float a = b2[c];
        for (int k = 0; k < 128; ++k) a = fmaf(h1[bb][k], w2[(size_t)k * 8 + c], a);
        out[i] = a;
    }
}

// ---------------------------------------------------------------------------
extern "C" void kernel_launch(void* const* d_in, const int* in_sizes, int n_in,
                              void* d_out, int out_size, void* d_ws, size_t ws_size,
                              hipStream_t stream)
{
    const float* wav  = (const float*)d_in[0];
    const float* cw   = (const float*)d_in[1];
    const float* pos  = (const float*)d_in[2];
    const float* lnsc = (const float*)d_in[3];
    const float* lnbi = (const float*)d_in[4];
    const float* wih  = (const float*)d_in[5];
    const float* whh  = (const float*)d_in[6];
    const float* bih  = (const float*)d_in[7];
    const float* bhh  = (const float*)d_in[8];
    const float* fsc  = (const float*)d_in[9];
    const float* fbi  = (const float*)d_in[10];
    const float* hw1  = (const float*)d_in[11];
    const float* hb1  = (const float*)d_in[12];
    const float* hw2  = (const float*)d_in[13];
    const float* hb2  = (const float*)d_in[14];

    float* ws    = (float*)d_ws;
    float* x     = ws;                        // 8,192,000 f
    float* xp    = x + (size_t)M_TOTAL * D;   // 24,576,000 f
    float* st    = xp + (size_t)M_TOTAL * G3; // 64,000 f
    float* whT   = st + 2 * M_TOTAL;          // 196,608 f
    float* emb   = whT + D * G3;              // 8,192 f
    unsigned long long* exch = (unsigned long long*)(emb + NB * D); // 49152 u64

    zero_exch<<<192, 256, 0, stream>>>(exch);  // 49152 u64
    conv_gelu_pos<<<dim3(M_TOTAL / 64, D / 64), 256, 0, stream>>>(wav, cw, pos, x);

    for (int l = 0; l < NL; ++l) {
        row_stats<<<M_TOTAL, 64, 0, stream>>>(x, st);
        ln_xp_gemm<<<dim3(M_TOTAL / 64, G3 / 64), 256, 0, stream>>>(
            x, st, lnsc + (size_t)l * D, lnbi + (size_t)l * D,
            wih + (size_t)l * G3 * D, bih + (size_t)l * G3, xp);
        transpose_whh<<<dim3(G3 / 32, D / 32), 256, 0, stream>>>(
            whh + (size_t)l * G3 * D, whT);
        gru_scan_ksplit<<<NB * 2, 512, 0, stream>>>(
            xp, whT, bhh + (size_t)l * G3, x, exch, l);
    }

    row_stats<<<M_TOTAL, 64, 0, stream>>>(x, st);
    pool_ln<<<NB, D, 0, stream>>>(x, st, fsc, fbi, emb);
    head_mlp<<<1, 256, 0, stream>>>(emb, hw1, hb1, hw2, hb2, (float*)d_out);
}